// Round 1
// baseline (683.699 us; speedup 1.0000x reference)
//
#include <hip/hip_runtime.h>
#include <math.h>

// Problem: B=64, C=512, H=64, W=64, E=16, K=4
// Kernel 1: fused max+avg pool over HxW per (b,c)  -> pooled[B*C] in d_ws
// Kernel 2: fc0+LeakyReLU, fc1+softplus, per-row normalize (ddof=1),
//           top-4 select, masked softmax -> gate[B,E]

#define HW 4096
#define CC 512
#define EE 16
#define KK 4

__global__ __launch_bounds__(256) void pool_kernel(const float* __restrict__ x,
                                                   float* __restrict__ pooled) {
    const int bc = blockIdx.x;  // 0 .. B*C-1
    const float4* xp = (const float4*)(x + (size_t)bc * HW);
    float mx = -INFINITY, sm = 0.f;
#pragma unroll
    for (int i = 0; i < 4; ++i) {
        float4 v = xp[threadIdx.x + i * 256];
        mx = fmaxf(mx, fmaxf(fmaxf(v.x, v.y), fmaxf(v.z, v.w)));
        sm += (v.x + v.y) + (v.z + v.w);
    }
    // wave-64 shuffle reduction
#pragma unroll
    for (int off = 32; off > 0; off >>= 1) {
        mx = fmaxf(mx, __shfl_down(mx, off, 64));
        sm += __shfl_down(sm, off, 64);
    }
    __shared__ float smx[4], ssm[4];
    const int wave = threadIdx.x >> 6;
    if ((threadIdx.x & 63) == 0) { smx[wave] = mx; ssm[wave] = sm; }
    __syncthreads();
    if (threadIdx.x == 0) {
        mx = fmaxf(fmaxf(smx[0], smx[1]), fmaxf(smx[2], smx[3]));
        sm = (ssm[0] + ssm[1]) + (ssm[2] + ssm[3]);
        pooled[bc] = mx + sm * (1.0f / (float)HW);
    }
}

__global__ __launch_bounds__(256) void gate_kernel(const float* __restrict__ pooled,
                                                   const float* __restrict__ W0,
                                                   const float* __restrict__ b0,
                                                   const float* __restrict__ W1,
                                                   const float* __restrict__ b1,
                                                   float* __restrict__ out) {
    const int b = blockIdx.x;  // 0 .. B-1
    __shared__ float sp[CC];
    __shared__ float sh[EE];   // h after LeakyReLU
    __shared__ float sn[EE];   // softplus noise
    sp[threadIdx.x]       = pooled[b * CC + threadIdx.x];
    sp[threadIdx.x + 256] = pooled[b * CC + 256 + threadIdx.x];
    __syncthreads();

    if (threadIdx.x < 2 * EE) {
        const int m = threadIdx.x >> 4;   // 0: fc0, 1: fc1
        const int e = threadIdx.x & 15;
        const float* Wrow = (m ? W1 : W0) + e * CC;
        float acc = 0.f;
#pragma unroll 8
        for (int c = 0; c < CC; ++c) acc = fmaf(sp[c], Wrow[c], acc);
        if (m == 0) {
            acc += b0[e];
            sh[e] = (acc >= 0.f) ? acc : 0.2f * acc;
        } else {
            acc += b1[e];
            // numerically stable softplus = max(x,0) + log1p(exp(-|x|))
            sn[e] = fmaxf(acc, 0.f) + log1pf(expf(-fabsf(acc)));
        }
    }
    __syncthreads();

    if (threadIdx.x == 0) {
        // per-row mean / std (ddof=1) over the 16 noise values
        float mu = 0.f;
#pragma unroll
        for (int e = 0; e < EE; ++e) mu += sn[e];
        mu *= (1.0f / (float)EE);
        float var = 0.f;
#pragma unroll
        for (int e = 0; e < EE; ++e) { float d = sn[e] - mu; var += d * d; }
        const float sd = sqrtf(var * (1.0f / (float)(EE - 1)));
        const float inv_sd = 1.0f / sd;

        float score[EE];
#pragma unroll
        for (int e = 0; e < EE; ++e) score[e] = sh[e] + (sn[e] - mu) * inv_sd;

        // top-4 selection (ties: lowest index first, matching lax.top_k)
        bool sel[EE];
#pragma unroll
        for (int e = 0; e < EE; ++e) sel[e] = false;
        for (int k = 0; k < KK; ++k) {
            int best = 0; float bv = -INFINITY;
            for (int e = 0; e < EE; ++e)
                if (!sel[e] && score[e] > bv) { bv = score[e]; best = e; }
            sel[best] = true;
        }

        // masked softmax over h
        float hmax = -INFINITY;
        for (int e = 0; e < EE; ++e) if (sel[e]) hmax = fmaxf(hmax, sh[e]);
        float ex[EE]; float den = 0.f;
        for (int e = 0; e < EE; ++e) {
            ex[e] = sel[e] ? expf(sh[e] - hmax) : 0.f;
            den += ex[e];
        }
        const float inv_den = 1.0f / den;
        for (int e = 0; e < EE; ++e) out[b * EE + e] = ex[e] * inv_den;
    }
}

extern "C" void kernel_launch(void* const* d_in, const int* in_sizes, int n_in,
                              void* d_out, int out_size, void* d_ws, size_t ws_size,
                              hipStream_t stream) {
    const float* x  = (const float*)d_in[0];  // [B, C, H, W]
    const float* W0 = (const float*)d_in[1];  // [E, C]
    const float* b0 = (const float*)d_in[2];  // [E]
    const float* W1 = (const float*)d_in[3];  // [E, C]
    const float* b1 = (const float*)d_in[4];  // [E]
    float* out = (float*)d_out;               // [B, E]
    float* pooled = (float*)d_ws;             // [B*C] = 32768 floats (128 KB)

    const int B = 64;
    pool_kernel<<<B * CC, 256, 0, stream>>>(x, pooled);
    gate_kernel<<<B, 256, 0, stream>>>(pooled, W0, b0, W1, b1, out);
}

// Round 2
// 676.628 us; speedup vs baseline: 1.0104x; 1.0104x over previous
//
#include <hip/hip_runtime.h>
#include <math.h>

// Problem: B=64, C=512, H=64, W=64, E=16, K=4
// Kernel 1: fused max+avg pool over HxW per (b,c)  -> pooled[B*C] in d_ws
//           wave-per-row: 4 waves/block, 16 rows/block, no LDS, no barriers
// Kernel 2: fc0+LeakyReLU, fc1+softplus, per-row normalize (ddof=1),
//           top-4 select, masked softmax -> gate[B,E]

#define HW 4096
#define CC 512
#define EE 16
#define KK 4
#define ROWS_PER_BLOCK 16

__global__ __launch_bounds__(256) void pool_kernel(const float* __restrict__ x,
                                                   float* __restrict__ pooled) {
    const int wave = threadIdx.x >> 6;
    const int lane = threadIdx.x & 63;
    const int base_row = blockIdx.x * ROWS_PER_BLOCK;
#pragma unroll
    for (int i = 0; i < ROWS_PER_BLOCK / 4; ++i) {
        const int row = base_row + i * 4 + wave;
        const float4* xp = (const float4*)(x + (size_t)row * HW);
        float mx = -INFINITY, sm = 0.f;
#pragma unroll
        for (int j = 0; j < 16; ++j) {
            float4 v = xp[lane + j * 64];
            mx = fmaxf(mx, fmaxf(fmaxf(v.x, v.y), fmaxf(v.z, v.w)));
            sm += (v.x + v.y) + (v.z + v.w);
        }
        // wave-64 shuffle reduction (no LDS, no barrier)
#pragma unroll
        for (int off = 32; off > 0; off >>= 1) {
            mx = fmaxf(mx, __shfl_down(mx, off, 64));
            sm += __shfl_down(sm, off, 64);
        }
        if (lane == 0) pooled[row] = mx + sm * (1.0f / (float)HW);
    }
}

__global__ __launch_bounds__(256) void gate_kernel(const float* __restrict__ pooled,
                                                   const float* __restrict__ W0,
                                                   const float* __restrict__ b0,
                                                   const float* __restrict__ W1,
                                                   const float* __restrict__ b1,
                                                   float* __restrict__ out) {
    const int b = blockIdx.x;  // 0 .. B-1
    __shared__ float4 sp[CC / 4];  // staged pooled row, 2 KB
    __shared__ float sh[EE];       // h after LeakyReLU
    __shared__ float sn[EE];       // softplus noise

    if (threadIdx.x < CC / 4)
        sp[threadIdx.x] = ((const float4*)(pooled + b * CC))[threadIdx.x];
    __syncthreads();

    // 32 outputs (2 matrices x 16 experts) x 8 threads each
    const int g = threadIdx.x >> 3;  // 0..31
    const int t = threadIdx.x & 7;
    const int m = g >> 4;            // 0: fc0, 1: fc1
    const int e = g & 15;
    const float4* W4 = (const float4*)((m ? W1 : W0) + e * CC);
    float acc = 0.f;
#pragma unroll
    for (int j = 0; j < 16; ++j) {
        const float4 w = W4[t + j * 8];
        const float4 p = sp[t + j * 8];
        acc = fmaf(w.x, p.x, acc);
        acc = fmaf(w.y, p.y, acc);
        acc = fmaf(w.z, p.z, acc);
        acc = fmaf(w.w, p.w, acc);
    }
    // reduce within the 8-lane group (lane-aligned within a wave)
    acc += __shfl_xor(acc, 4, 64);
    acc += __shfl_xor(acc, 2, 64);
    acc += __shfl_xor(acc, 1, 64);
    if (t == 0) {
        if (m == 0) {
            const float v = acc + b0[e];
            sh[e] = (v >= 0.f) ? v : 0.2f * v;
        } else {
            const float v = acc + b1[e];
            // numerically stable softplus = max(x,0) + log1p(exp(-|x|))
            sn[e] = fmaxf(v, 0.f) + log1pf(expf(-fabsf(v)));
        }
    }
    __syncthreads();

    if (threadIdx.x == 0) {
        // per-row mean / std (ddof=1) over the 16 noise values
        float mu = 0.f;
#pragma unroll
        for (int e2 = 0; e2 < EE; ++e2) mu += sn[e2];
        mu *= (1.0f / (float)EE);
        float var = 0.f;
#pragma unroll
        for (int e2 = 0; e2 < EE; ++e2) { float d = sn[e2] - mu; var += d * d; }
        const float sd = sqrtf(var * (1.0f / (float)(EE - 1)));
        const float inv_sd = 1.0f / sd;

        float score[EE];
#pragma unroll
        for (int e2 = 0; e2 < EE; ++e2) score[e2] = sh[e2] + (sn[e2] - mu) * inv_sd;

        // top-4 selection (ties: lowest index first, matching lax.top_k)
        bool sel[EE];
#pragma unroll
        for (int e2 = 0; e2 < EE; ++e2) sel[e2] = false;
        for (int k = 0; k < KK; ++k) {
            int best = 0; float bv = -INFINITY;
            for (int e2 = 0; e2 < EE; ++e2)
                if (!sel[e2] && score[e2] > bv) { bv = score[e2]; best = e2; }
            sel[best] = true;
        }

        // masked softmax over h
        float hmax = -INFINITY;
        for (int e2 = 0; e2 < EE; ++e2) if (sel[e2]) hmax = fmaxf(hmax, sh[e2]);
        float ex[EE]; float den = 0.f;
        for (int e2 = 0; e2 < EE; ++e2) {
            ex[e2] = sel[e2] ? expf(sh[e2] - hmax) : 0.f;
            den += ex[e2];
        }
        const float inv_den = 1.0f / den;
        for (int e2 = 0; e2 < EE; ++e2) out[b * EE + e2] = ex[e2] * inv_den;
    }
}

extern "C" void kernel_launch(void* const* d_in, const int* in_sizes, int n_in,
                              void* d_out, int out_size, void* d_ws, size_t ws_size,
                              hipStream_t stream) {
    const float* x  = (const float*)d_in[0];  // [B, C, H, W]
    const float* W0 = (const float*)d_in[1];  // [E, C]
    const float* b0 = (const float*)d_in[2];  // [E]
    const float* W1 = (const float*)d_in[3];  // [E, C]
    const float* b1 = (const float*)d_in[4];  // [E]
    float* out = (float*)d_out;               // [B, E]
    float* pooled = (float*)d_ws;             // [B*C] = 32768 floats (128 KB)

    const int B = 64;
    pool_kernel<<<(B * CC) / ROWS_PER_BLOCK, 256, 0, stream>>>(x, pooled);
    gate_kernel<<<B, 256, 0, stream>>>(pooled, W0, b0, W1, b1, out);
}